// Round 15
// baseline (129.634 us; speedup 1.0000x reference)
//
#include <hip/hip_runtime.h>

typedef unsigned short u16;
typedef unsigned int   u32;
typedef __bf16 bf16x8 __attribute__((ext_vector_type(8)));
typedef u16    u16x8  __attribute__((ext_vector_type(8)));
typedef float  f32x4  __attribute__((ext_vector_type(4)));

#define T_TOT  65536
#define NSEG   64
#define NH     16
#define DD     128
#define LL     64
#define BT     64
#define CHUNK  512           // frames per block
#define NTILE  8             // CHUNK / BT
#define NCHUNK 128           // T_TOT / CHUNK
#define LDA    136           // u16 row stride (272 B): b128 reads ~conflict-free (measured R6)
#define SCALE  11.313708498984761f   // sqrt(128)

__device__ __forceinline__ u16 f2bf_rne(float x){
    u32 u = __float_as_uint(x);
    u32 r = u + 0x7fffu + ((u >> 16) & 1u);
    return (u16)(r >> 16);
}
__device__ __forceinline__ float bf2f(u16 h){
    return __uint_as_float(((u32)h) << 16);
}
__device__ __forceinline__ float fast_tanh(float x){
    float e = __builtin_amdgcn_exp2f(x * 2.8853900817779268f);  // 2*log2(e)
    return 1.0f - 2.0f * __builtin_amdgcn_rcpf(1.0f + e);
}

// sum across the 16-lane group via DPP (VALU-only)
__device__ __forceinline__ float row16_sum(float x){
    int v;
    v = __builtin_amdgcn_update_dpp(0, __float_as_int(x), 0xB1, 0xf, 0xf, true);  // quad_perm(1,0,3,2)
    x += __int_as_float(v);
    v = __builtin_amdgcn_update_dpp(0, __float_as_int(x), 0x4E, 0xf, 0xf, true);  // quad_perm(2,3,0,1)
    x += __int_as_float(v);
    v = __builtin_amdgcn_update_dpp(0, __float_as_int(x), 0x124, 0xf, 0xf, true); // row_ror:4
    x += __int_as_float(v);
    v = __builtin_amdgcn_update_dpp(0, __float_as_int(x), 0x128, 0xf, 0xf, true); // row_ror:8
    x += __int_as_float(v);
    return x;
}

// split 8 fp32 -> bf16 hi + lo via HW cvt (RNE)
__device__ __forceinline__ void cvt8(const float4 a, const float4 b,
                                     bf16x8& hi, bf16x8& lo){
    float xs[8] = {a.x, a.y, a.z, a.w, b.x, b.y, b.z, b.w};
    #pragma unroll
    for (int j = 0; j < 8; ++j){
        __bf16 h = (__bf16)xs[j];
        hi[j] = h;
        lo[j] = (__bf16)(xs[j] - (float)h);
    }
}

// ---------------- prep: split V into bf16 hi/lo + zero accumulators ----------------
__global__ void prep_split(const float* __restrict__ V,
                           u16* __restrict__ Vh, u16* __restrict__ Vl,
                           float* __restrict__ hsum, float* __restrict__ denom){
    int idx = blockIdx.x * 256 + threadIdx.x;   // 131072 threads
    float x = V[idx];
    u16 hi = f2bf_rne(x);
    Vh[idx] = hi;
    Vl[idx] = f2bf_rne(x - bf2f(hi));
    hsum[idx] = 0.0f;                            // hsum is exactly 131072 floats
    if (idx < NSEG * NH) denom[idx] = 0.0f;
}

// one tile: cvt(AV) -> park -> prefetch tile PT into AV (3 tiles ahead) -> MFMA -> softmax -> phase-4
#define TILE_BODY(AV, TT, PT)                                                            \
{                                                                                        \
    bf16x8 aHk[4], aLk[4];                                                               \
    _Pragma("unroll")                                                                    \
    for (int ks = 0; ks < 4; ++ks){                                                      \
        cvt8(AV[2*ks], AV[2*ks+1], aHk[ks], aLk[ks]);                                    \
        *(bf16x8*)(parkp + ks * 32) = aHk[ks];                                           \
    }                                                                                    \
    if ((PT) < NTILE){                                                                   \
        const float* nrow = arow + (size_t)(PT) * BT * 2048;                             \
        _Pragma("unroll")                                                                \
        for (int q = 0; q < 4; ++q){                                                     \
            AV[2*q]   = *(const float4*)(nrow + q * 32);                                 \
            AV[2*q+1] = *(const float4*)(nrow + q * 32 + 4);                             \
        }                                                                                \
    }                                                                                    \
    f32x4 acc[4] = {};                                                                   \
    _Pragma("unroll")                                                                    \
    for (int ks = 0; ks < 4; ++ks){                                                      \
        _Pragma("unroll")                                                                \
        for (int nt = 0; nt < 4; ++nt){                                                  \
            const int boff = (nt * 16 + col) * LDA + kb * 8 + ks * 32;                   \
            bf16x8 bH = *(const bf16x8*)(sBh + boff);                                    \
            bf16x8 bL = *(const bf16x8*)(sBl + boff);                                    \
            acc[nt] = __builtin_amdgcn_mfma_f32_16x16x32_bf16(aHk[ks], bH, acc[nt], 0, 0, 0); \
            acc[nt] = __builtin_amdgcn_mfma_f32_16x16x32_bf16(aLk[ks], bH, acc[nt], 0, 0, 0); \
            acc[nt] = __builtin_amdgcn_mfma_f32_16x16x32_bf16(aHk[ks], bL, acc[nt], 0, 0, 0); \
        }                                                                                \
    }                                                                                    \
    float e4[4];                                                                         \
    _Pragma("unroll")                                                                    \
    for (int r = 0; r < 4; ++r){                                                         \
        float s = 0.f;                                                                   \
        _Pragma("unroll")                                                                \
        for (int nt = 0; nt < 4; ++nt)                                                   \
            s += fast_tanh(acc[nt][r]) * wl[nt];                                         \
        s = row16_sum(s);                                                                \
        e4[r] = __builtin_amdgcn_exp2f(s * 1.4426950408889634f);                         \
    }                                                                                    \
    const int msel = ((TT) < 4) ? mseg0 : mseg1;                                         \
    const int tb   = ((TT) & 3) * 16;                                                    \
    _Pragma("unroll")                                                                    \
    for (int j = 0; j < 16; ++j){                                                        \
        float ej = __int_as_float(__builtin_amdgcn_readlane(__float_as_int(e4[j & 3]), (j >> 2) * 16)); \
        int   s  = __builtin_amdgcn_readlane(msel, tb + j);                              \
        if (s != cur){                                                                   \
            if (cur >= 0){                                                               \
                float* dst = hsum + ((size_t)cur * NH + h) * DD + lane * 2;              \
                atomicAdd(dst, ax); atomicAdd(dst + 1, ay);                              \
                if (lane == 0) atomicAdd(&denom[cur * NH + h], dn);                      \
            }                                                                            \
            ax = 0.f; ay = 0.f; dn = 0.f; cur = s;                                       \
        }                                                                                \
        u32 uh = *(const u32*)(rdp + j * LDA);                                           \
        ax += ej * __uint_as_float(uh << 16);                                            \
        ay += ej * __uint_as_float(uh & 0xffff0000u);                                    \
        dn += ej;                                                                        \
    }                                                                                    \
}

// ---------------- main: heads-fastest grid, B hi+lo in LDS, depth-3 A prefetch, (256,2) ----------------
__global__ __launch_bounds__(256, 2) void medvid_main(
    const float* __restrict__ videos, const int* __restrict__ segids,
    const u16* __restrict__ Vh, const u16* __restrict__ Vl,
    const float* __restrict__ w,
    float* __restrict__ hsum, float* __restrict__ denom)
{
    __shared__ u16 sAh[BT * LDA];   // A-hi park (17.4 KB)
    __shared__ u16 sBh[LL * LDA];   // B-hi tile (17.4 KB)
    __shared__ u16 sBl[LL * LDA];   // B-lo tile (17.4 KB)

    const int tid  = threadIdx.x;
    const int h    = blockIdx.x;            // heads vary fastest in dispatch order
    const int c0   = blockIdx.y * CHUNK;
    const int lane = tid & 63;
    const int wv   = tid >> 6;      // wave id = 16-frame strip within tile
    const int col  = lane & 15;
    const int kb   = lane >> 4;

    // ---- stage B hi+lo into LDS (once per block) ----
    #pragma unroll
    for (int i = 0; i < 8; ++i){
        int idx = i * 256 + tid;            // 2048 chunks of 16 B
        int half = idx >> 10;               // 0 -> hi, 1 -> lo (uniform per i)
        int rem  = idx & 1023;
        int l = rem >> 4, c = rem & 15;
        u16* dst = half ? sBl : sBh;
        const u16* src = half ? Vl : Vh;
        *(uint4*)(dst + l * LDA + c * 8) = *(const uint4*)(src + (h * LL + l) * DD + c * 8);
    }

    float wl[4];
    #pragma unroll
    for (int nt = 0; nt < 4; ++nt) wl[nt] = w[h * LL + nt * 16 + col];

    // ---- this wave's 128 segment ids (2 regs/lane) ----
    const int segbase = c0 + kb * 64 + wv * 16 + col;
    const int mseg0 = segids[segbase];
    const int mseg1 = segids[segbase + 256];

    // ---- prologue: tiles 0,1,2 in flight (depth-3) ----
    const float* arow = videos + (size_t)(c0 + wv * 16 + col) * 2048 + h * DD + kb * 8;
    float4 avA[8], avB[8], avC[8];
    #pragma unroll
    for (int q = 0; q < 4; ++q){
        avA[2*q]   = *(const float4*)(arow + q * 32);
        avA[2*q+1] = *(const float4*)(arow + q * 32 + 4);
    }
    {
        const float* nrow = arow + (size_t)BT * 2048;
        #pragma unroll
        for (int q = 0; q < 4; ++q){
            avB[2*q]   = *(const float4*)(nrow + q * 32);
            avB[2*q+1] = *(const float4*)(nrow + q * 32 + 4);
        }
        nrow += (size_t)BT * 2048;
        #pragma unroll
        for (int q = 0; q < 4; ++q){
            avC[2*q]   = *(const float4*)(nrow + q * 32);
            avC[2*q+1] = *(const float4*)(nrow + q * 32 + 4);
        }
    }

    u16*       parkp = sAh + (wv * 16 + col) * LDA + kb * 8;
    const u16* rdp   = sAh + (wv * 16) * LDA + lane * 2;

    __syncthreads();   // B tiles visible

    int   cur = -1;
    float ax = 0.f, ay = 0.f, dn = 0.f;

    // depth-3 rotation, fully unrolled (static tile indices)
    TILE_BODY(avA, 0, 3)
    TILE_BODY(avB, 1, 4)
    TILE_BODY(avC, 2, 5)
    TILE_BODY(avA, 3, 6)
    TILE_BODY(avB, 4, 7)
    TILE_BODY(avC, 5, 8)
    TILE_BODY(avA, 6, 9)
    TILE_BODY(avB, 7, 10)

    // ---- final flush ----
    if (cur >= 0){
        float* dst = hsum + ((size_t)cur * NH + h) * DD + lane * 2;
        atomicAdd(dst, ax); atomicAdd(dst + 1, ay);
        if (lane == 0) atomicAdd(&denom[cur * NH + h], dn);
    }
}

// ---------------- finalize ----------------
__global__ void finalize(const float* __restrict__ hsum, const float* __restrict__ denom,
                         const float* __restrict__ W_out, const float* __restrict__ b_out,
                         float* __restrict__ out)
{
    const int s = blockIdx.x;
    const int tid = threadIdx.x;
    float part = 0.f;
    for (int f = tid; f < 2048; f += 256){
        int hh = f >> 7, d = f & 127;
        float den = denom[s * NH + hh];
        if (den > 0.f)
            part += hsum[((size_t)s * NH + hh) * DD + d] / (den * SCALE) * W_out[f];
    }
    #pragma unroll
    for (int m = 1; m < 64; m <<= 1) part += __shfl_xor(part, m, 64);
    __shared__ float red[4];
    if ((tid & 63) == 0) red[tid >> 6] = part;
    __syncthreads();
    if (tid == 0) out[s] = red[0] + red[1] + red[2] + red[3] + b_out[0];
}

extern "C" void kernel_launch(void* const* d_in, const int* in_sizes, int n_in,
                              void* d_out, int out_size, void* d_ws, size_t ws_size,
                              hipStream_t stream)
{
    const float* videos = (const float*)d_in[0];
    const int*   segids = (const int*)  d_in[1];
    const float* V      = (const float*)d_in[2];
    const float* w      = (const float*)d_in[3];
    const float* W_out  = (const float*)d_in[4];
    const float* b_out  = (const float*)d_in[5];
    float* out = (float*)d_out;

    // ws layout: hsum[S*H*D] f32 | denom[S*H] f32 | Vh[H*L*D] u16 | Vl[H*L*D] u16
    float* hsum  = (float*)d_ws;
    float* denom = hsum + (NSEG * NH * DD);
    u16*   Vh    = (u16*)(denom + NSEG * NH);
    u16*   Vl    = Vh + (NH * LL * DD);

    prep_split<<<dim3((NH * LL * DD) / 256), dim3(256), 0, stream>>>(V, Vh, Vl, hsum, denom);
    medvid_main<<<dim3(NH, NCHUNK), dim3(256), 0, stream>>>(videos, segids, Vh, Vl, w, hsum, denom);
    finalize<<<dim3(NSEG), dim3(256), 0, stream>>>(hsum, denom, W_out, b_out, out);
}

// Round 16
// 124.774 us; speedup vs baseline: 1.0389x; 1.0389x over previous
//
#include <hip/hip_runtime.h>

typedef unsigned short u16;
typedef unsigned int   u32;
typedef __bf16 bf16x8 __attribute__((ext_vector_type(8)));
typedef u16    u16x8  __attribute__((ext_vector_type(8)));
typedef float  f32x4  __attribute__((ext_vector_type(4)));

#define T_TOT  65536
#define NSEG   64
#define NH     16
#define DD     128
#define LL     64
#define BT     64
#define CHUNK  512           // frames per block
#define NTILE  8             // CHUNK / BT
#define NCHUNK 128           // T_TOT / CHUNK
#define LDA    136           // u16 row stride (272 B): b128 reads ~conflict-free (measured R6)
#define SCALE  11.313708498984761f   // sqrt(128)

__device__ __forceinline__ float fast_tanh(float x){
    float e = __builtin_amdgcn_exp2f(x * 2.8853900817779268f);  // 2*log2(e)
    return 1.0f - 2.0f * __builtin_amdgcn_rcpf(1.0f + e);
}

// sum across the 16-lane group via DPP (VALU-only)
__device__ __forceinline__ float row16_sum(float x){
    int v;
    v = __builtin_amdgcn_update_dpp(0, __float_as_int(x), 0xB1, 0xf, 0xf, true);  // quad_perm(1,0,3,2)
    x += __int_as_float(v);
    v = __builtin_amdgcn_update_dpp(0, __float_as_int(x), 0x4E, 0xf, 0xf, true);  // quad_perm(2,3,0,1)
    x += __int_as_float(v);
    v = __builtin_amdgcn_update_dpp(0, __float_as_int(x), 0x124, 0xf, 0xf, true); // row_ror:4
    x += __int_as_float(v);
    v = __builtin_amdgcn_update_dpp(0, __float_as_int(x), 0x128, 0xf, 0xf, true); // row_ror:8
    x += __int_as_float(v);
    return x;
}

// split 8 fp32 -> bf16 hi + lo via HW cvt (RNE)
__device__ __forceinline__ void cvt8(const float4 a, const float4 b,
                                     bf16x8& hi, bf16x8& lo){
    float xs[8] = {a.x, a.y, a.z, a.w, b.x, b.y, b.z, b.w};
    #pragma unroll
    for (int j = 0; j < 8; ++j){
        __bf16 h = (__bf16)xs[j];
        hi[j] = h;
        lo[j] = (__bf16)(xs[j] - (float)h);
    }
}

// ---------------- prep: zero accumulators (V split is fused into main's staging) ----------------
__global__ void prep_zero(float* __restrict__ hsum, float* __restrict__ denom){
    int idx = blockIdx.x * 256 + threadIdx.x;   // 131072 threads
    hsum[idx] = 0.0f;                            // hsum is exactly 131072 floats
    if (idx < NSEG * NH) denom[idx] = 0.0f;
}

// one tile: cvt(AV) -> park -> prefetch tile PT into AV (2 tiles ahead) -> MFMA -> softmax -> phase-4
#define TILE_BODY(AV, TT, PT)                                                            \
{                                                                                        \
    bf16x8 aHk[4], aLk[4];                                                               \
    _Pragma("unroll")                                                                    \
    for (int ks = 0; ks < 4; ++ks){                                                      \
        cvt8(AV[2*ks], AV[2*ks+1], aHk[ks], aLk[ks]);                                    \
        *(bf16x8*)(parkp + ks * 32) = aHk[ks];                                           \
    }                                                                                    \
    if ((PT) < NTILE){                                                                   \
        const float* nrow = arow + (size_t)(PT) * BT * 2048;                             \
        _Pragma("unroll")                                                                \
        for (int q = 0; q < 4; ++q){                                                     \
            AV[2*q]   = *(const float4*)(nrow + q * 32);                                 \
            AV[2*q+1] = *(const float4*)(nrow + q * 32 + 4);                             \
        }                                                                                \
    }                                                                                    \
    f32x4 acc[4] = {};                                                                   \
    _Pragma("unroll")                                                                    \
    for (int ks = 0; ks < 4; ++ks){                                                      \
        _Pragma("unroll")                                                                \
        for (int nt = 0; nt < 4; ++nt){                                                  \
            const int boff = (nt * 16 + col) * LDA + kb * 8 + ks * 32;                   \
            bf16x8 bH = *(const bf16x8*)(sBh + boff);                                    \
            bf16x8 bL = *(const bf16x8*)(sBl + boff);                                    \
            acc[nt] = __builtin_amdgcn_mfma_f32_16x16x32_bf16(aHk[ks], bH, acc[nt], 0, 0, 0); \
            acc[nt] = __builtin_amdgcn_mfma_f32_16x16x32_bf16(aLk[ks], bH, acc[nt], 0, 0, 0); \
            acc[nt] = __builtin_amdgcn_mfma_f32_16x16x32_bf16(aHk[ks], bL, acc[nt], 0, 0, 0); \
        }                                                                                \
    }                                                                                    \
    float e4[4];                                                                         \
    _Pragma("unroll")                                                                    \
    for (int r = 0; r < 4; ++r){                                                         \
        float s = 0.f;                                                                   \
        _Pragma("unroll")                                                                \
        for (int nt = 0; nt < 4; ++nt)                                                   \
            s += fast_tanh(acc[nt][r]) * wl[nt];                                         \
        s = row16_sum(s);                                                                \
        e4[r] = __builtin_amdgcn_exp2f(s * 1.4426950408889634f);                         \
    }                                                                                    \
    const int msel = ((TT) < 4) ? mseg0 : mseg1;                                         \
    const int tb   = ((TT) & 3) * 16;                                                    \
    _Pragma("unroll")                                                                    \
    for (int j = 0; j < 16; ++j){                                                        \
        float ej = __int_as_float(__builtin_amdgcn_readlane(__float_as_int(e4[j & 3]), (j >> 2) * 16)); \
        int   s  = __builtin_amdgcn_readlane(msel, tb + j);                              \
        if (s != cur){                                                                   \
            if (cur >= 0){                                                               \
                float* dst = hsum + ((size_t)cur * NH + h) * DD + lane * 2;              \
                atomicAdd(dst, ax); atomicAdd(dst + 1, ay);                              \
                if (lane == 0) atomicAdd(&denom[cur * NH + h], dn);                      \
            }                                                                            \
            ax = 0.f; ay = 0.f; dn = 0.f; cur = s;                                       \
        }                                                                                \
        u32 uh = *(const u32*)(rdp + j * LDA);                                           \
        ax += ej * __uint_as_float(uh << 16);                                            \
        ay += ej * __uint_as_float(uh & 0xffff0000u);                                    \
        dn += ej;                                                                        \
    }                                                                                    \
}

// ---------------- main: heads-fastest grid, fused V split -> B hi+lo in LDS, depth-2, (256,2) ----------------
__global__ __launch_bounds__(256, 2) void medvid_main(
    const float* __restrict__ videos, const int* __restrict__ segids,
    const float* __restrict__ V, const float* __restrict__ w,
    float* __restrict__ hsum, float* __restrict__ denom)
{
    __shared__ u16 sAh[BT * LDA];   // A-hi park (17.4 KB)
    __shared__ u16 sBh[LL * LDA];   // B-hi tile (17.4 KB)
    __shared__ u16 sBl[LL * LDA];   // B-lo tile (17.4 KB)

    const int tid  = threadIdx.x;
    const int h    = blockIdx.x;            // heads vary fastest in dispatch order
    const int c0   = blockIdx.y * CHUNK;
    const int lane = tid & 63;
    const int wv   = tid >> 6;      // wave id = 16-frame strip within tile
    const int col  = lane & 15;
    const int kb   = lane >> 4;

    // ---- stage B: read V[h] fp32 (L2-resident), split hi/lo in-register, write both tiles ----
    #pragma unroll
    for (int i = 0; i < 8; ++i){
        int idx = i * 256 + tid;            // 2048 float4 chunks (64 x 128 fp32)
        int l = idx >> 5, c = idx & 31;     // 32 float4 per row
        float4 v = *(const float4*)(V + (h * LL + l) * DD + c * 4);
        ushort4 hi4, lo4;
        {
            __bf16 b0 = (__bf16)v.x; hi4.x = *(u16*)&b0; __bf16 l0 = (__bf16)(v.x - (float)b0); lo4.x = *(u16*)&l0;
            __bf16 b1 = (__bf16)v.y; hi4.y = *(u16*)&b1; __bf16 l1 = (__bf16)(v.y - (float)b1); lo4.y = *(u16*)&l1;
            __bf16 b2 = (__bf16)v.z; hi4.z = *(u16*)&b2; __bf16 l2 = (__bf16)(v.z - (float)b2); lo4.z = *(u16*)&l2;
            __bf16 b3 = (__bf16)v.w; hi4.w = *(u16*)&b3; __bf16 l3 = (__bf16)(v.w - (float)b3); lo4.w = *(u16*)&l3;
        }
        *(ushort4*)(sBh + l * LDA + c * 4) = hi4;
        *(ushort4*)(sBl + l * LDA + c * 4) = lo4;
    }

    float wl[4];
    #pragma unroll
    for (int nt = 0; nt < 4; ++nt) wl[nt] = w[h * LL + nt * 16 + col];

    // ---- this wave's 128 segment ids (2 regs/lane) ----
    const int segbase = c0 + kb * 64 + wv * 16 + col;
    const int mseg0 = segids[segbase];
    const int mseg1 = segids[segbase + 256];

    // ---- prologue: tiles 0 and 1 in flight (depth-2) ----
    const float* arow = videos + (size_t)(c0 + wv * 16 + col) * 2048 + h * DD + kb * 8;
    float4 avA[8], avB[8];
    #pragma unroll
    for (int q = 0; q < 4; ++q){
        avA[2*q]   = *(const float4*)(arow + q * 32);
        avA[2*q+1] = *(const float4*)(arow + q * 32 + 4);
    }
    {
        const float* nrow = arow + (size_t)BT * 2048;
        #pragma unroll
        for (int q = 0; q < 4; ++q){
            avB[2*q]   = *(const float4*)(nrow + q * 32);
            avB[2*q+1] = *(const float4*)(nrow + q * 32 + 4);
        }
    }

    u16*       parkp = sAh + (wv * 16 + col) * LDA + kb * 8;
    const u16* rdp   = sAh + (wv * 16) * LDA + lane * 2;

    __syncthreads();   // B tiles visible

    int   cur = -1;
    float ax = 0.f, ay = 0.f, dn = 0.f;

    for (int tp = 0; tp < NTILE / 2; ++tp){
        const int tA = 2 * tp, tB = 2 * tp + 1;
        TILE_BODY(avA, tA, tA + 2)
        TILE_BODY(avB, tB, tB + 2)
    }
    // ---- final flush ----
    if (cur >= 0){
        float* dst = hsum + ((size_t)cur * NH + h) * DD + lane * 2;
        atomicAdd(dst, ax); atomicAdd(dst + 1, ay);
        if (lane == 0) atomicAdd(&denom[cur * NH + h], dn);
    }
}

// ---------------- finalize ----------------
__global__ void finalize(const float* __restrict__ hsum, const float* __restrict__ denom,
                         const float* __restrict__ W_out, const float* __restrict__ b_out,
                         float* __restrict__ out)
{
    const int s = blockIdx.x;
    const int tid = threadIdx.x;
    float part = 0.f;
    for (int f = tid; f < 2048; f += 256){
        int hh = f >> 7, d = f & 127;
        float den = denom[s * NH + hh];
        if (den > 0.f)
            part += hsum[((size_t)s * NH + hh) * DD + d] / (den * SCALE) * W_out[f];
    }
    #pragma unroll
    for (int m = 1; m < 64; m <<= 1) part += __shfl_xor(part, m, 64);
    __shared__ float red[4];
    if ((tid & 63) == 0) red[tid >> 6] = part;
    __syncthreads();
    if (tid == 0) out[s] = red[0] + red[1] + red[2] + red[3] + b_out[0];
}

extern "C" void kernel_launch(void* const* d_in, const int* in_sizes, int n_in,
                              void* d_out, int out_size, void* d_ws, size_t ws_size,
                              hipStream_t stream)
{
    const float* videos = (const float*)d_in[0];
    const int*   segids = (const int*)  d_in[1];
    const float* V      = (const float*)d_in[2];
    const float* w      = (const float*)d_in[3];
    const float* W_out  = (const float*)d_in[4];
    const float* b_out  = (const float*)d_in[5];
    float* out = (float*)d_out;

    // ws layout: hsum[S*H*D] f32 | denom[S*H] f32
    float* hsum  = (float*)d_ws;
    float* denom = hsum + (NSEG * NH * DD);

    prep_zero<<<dim3((NSEG * NH * DD) / 256), dim3(256), 0, stream>>>(hsum, denom);
    medvid_main<<<dim3(NH, NCHUNK), dim3(256), 0, stream>>>(videos, segids, V, w, hsum, denom);
    finalize<<<dim3(NSEG), dim3(256), 0, stream>>>(hsum, denom, W_out, b_out, out);
}